// Round 7
// baseline (223.795 us; speedup 1.0000x reference)
//
#include <hip/hip_runtime.h>

// SimpleRNN fused kernel for MI355X (gfx950).  B=32768, T=28, I=28, H=128, C=10.
//
// R14: amortize the per-step barrier over 2x the batches.
// Cross-round facts driving this design (R7..R13):
//   - VALU busy-time is invariant ~50 us across all structures; wall = 2x busy
//     -> per-step barrier/chain overhead C ~= per-step work W.
//   - Occupancy pins at ~13 waves/CU no matter the LDS/VGPR headroom (4 rounds
//     of evidence) -> residency knobs are dead; amortization is the lever.
//   - W-replication per wave (R8/R12: 128+ VGPRs) kills residency -> keep W
//     SHARED across 4 waves (48 persistent regs, R7-proven).
//   - __syncthreads' vmcnt(0) drain with in-loop global x cost +15 us (R11);
//     lgkm-only raw barrier fixes that (cross-wave deps are LDS-only; x loads
//     are wave-private).  R9's failure was the pk-f32 tanh asm, not this.
// Structure:
//   - Block = 256 thr / 4 waves owns 32 batches; wave w: h rows [32w,32w+32)
//     (2 m-tiles) x 2 n-tiles (batches 0-15, 16-31).  20 MFMA + 4 tanh4 +
//     8 frag-reads + 4 b64 writes per step per wave; ONE barrier per step
//     for 32 batches (R7: one per 16).
//   - Sbuf[2][32*132] u16 = 16.9 KB, stride-132 (measured conflict-ok
//     R1/R3/R5/R10).  No Xbuf: x streamed from global, 1-step prefetch
//     (R11-proven addressing/numerics), raw lgkm-only barrier keeps those
//     loads in flight.
//   - scalar Pade(5,4) tanh (best measured), bias-as-MFMA-C.
//   - grid 1024 = 4 blocks/CU of work; launch_bounds(256,4) (VGPR cap 128,
//     est. ~110; spill signature = WRITE_SIZE blowup, watched).
// MFMA 16x16x32 bf16 layouts (m89/m91):
//   A[m=lane&15][k=(lane>>4)*8+j]  B[k=(lane>>4)*8+j][n=lane&15]
//   D[(lane>>4)*4+r][lane&15]

#define T_STEPS 28
#define S_STRIDE 132

typedef __attribute__((ext_vector_type(4))) float f32x4;
typedef __attribute__((ext_vector_type(8))) short short8;

#define MFMA16 __builtin_amdgcn_mfma_f32_16x16x32_bf16

__device__ __forceinline__ unsigned pack2(float lo, float hi) {
#if __has_builtin(__builtin_amdgcn_cvt_pk_bf16_f32)
  auto p = __builtin_amdgcn_cvt_pk_bf16_f32(lo, hi);   // RNE pack, 1 inst
  return __builtin_bit_cast(unsigned, p);
#else
  unsigned a = __builtin_bit_cast(unsigned, lo);
  a += 0x7FFFu + ((a >> 16) & 1u);
  unsigned b = __builtin_bit_cast(unsigned, hi);
  b += 0x7FFFu + ((b >> 16) & 1u);
  return (a >> 16) | (b & 0xFFFF0000u);
#endif
}

__device__ __forceinline__ short8 to_frag(f32x4 a, f32x4 b) {
  union { unsigned u[4]; short8 v; } r;
  r.u[0] = pack2(a[0], a[1]);
  r.u[1] = pack2(a[2], a[3]);
  r.u[2] = pack2(b[0], b[1]);
  r.u[3] = pack2(b[2], b[3]);
  return r.v;
}

__device__ __forceinline__ short8 load_frag64(const unsigned short* sp, int off) {
  // two b64 reads; measured conflict-free at the stride-132 pattern (R1/R3/R5/R10)
  union { uint2 d[2]; short8 v; } r;
  r.d[0] = *(const uint2*)(sp + off);
  r.d[1] = *(const uint2*)(sp + off + 4);
  return r.v;
}

// Pade(5,4) tanh, scalar fp32 (best measured, R4): max err ~1.2e-3, den>=945.
__device__ __forceinline__ f32x4 tanh4(f32x4 z) {
  f32x4 x2 = z * z;
  f32x4 p = 945.0f + x2 * (105.0f + x2);
  f32x4 q = 945.0f + x2 * (420.0f + 15.0f * x2);
  f32x4 num = z * p;
  f32x4 r;
#pragma unroll
  for (int i = 0; i < 4; ++i) r[i] = __builtin_amdgcn_rcpf(q[i]);
  f32x4 t = num * r;
#pragma unroll
  for (int i = 0; i < 4; ++i) t[i] = __builtin_amdgcn_fmed3f(t[i], -1.0f, 1.0f);
  return t;
}

// Barrier with LDS-only drain: ds_writes/reads complete (lgkmcnt), global
// x prefetch stays in flight (no vmcnt drain; those loads are wave-private).
__device__ __forceinline__ void lds_barrier() {
  asm volatile("s_waitcnt lgkmcnt(0)" ::: "memory");
  __builtin_amdgcn_s_barrier();
  asm volatile("" ::: "memory");
}

__global__ __launch_bounds__(256, 4) void rnn_fused(
    const float* __restrict__ x,  const float* __restrict__ Uw,
    const float* __restrict__ Ub, const float* __restrict__ Ww,
    const float* __restrict__ Wb, const float* __restrict__ Vw,
    const float* __restrict__ Vb, float* __restrict__ out) {
  __shared__ __align__(16) unsigned short Sbuf[2][32 * S_STRIDE];  // 16896 B

  const int tid  = threadIdx.x;
  const int w    = tid >> 6;
  const int lane = tid & 63;
  const int l15  = lane & 15;
  const int q    = lane >> 4;           // 0..3
  const int mrow = w * 32;              // h base for this wave (2 m-tiles)
  const int b0   = blockIdx.x * 32;

  const f32x4 zero4 = {0.f, 0.f, 0.f, 0.f};

  // ---- x streaming: 2 n-tiles, batch = b0 + nt*16 + l15, i = q*8..q*8+7 ----
  const float* xp0 = x + (size_t)(b0 + l15) * 784 + q * 8;
  const float* xp1 = xp0 + 16 * 784;
  f32x4 xa0 = *(const f32x4*)xp0, xa1 = *(const f32x4*)xp1;
  f32x4 xb0 = zero4, xb1 = zero4;
  if (q < 3) { xb0 = *(const f32x4*)(xp0 + 4); xb1 = *(const f32x4*)(xp1 + 4); }

  // ---- persistent weight fragments (shared role split across 4 waves) ----
  short8 wfrag[2][4];   // [mt][kt]
  short8 ufrag[2];      // [mt], K=32 padded (k>=28 zeroed)
  f32x4  bias[2];       // Ub[h]+Wb[h] at D rows h = mrow + mt*16 + q*4 + r
#pragma unroll
  for (int mt = 0; mt < 2; ++mt) {
    const int h = mrow + mt * 16 + l15;
    const float* wp = Ww + h * 128 + q * 8;
#pragma unroll
    for (int kt = 0; kt < 4; ++kt) {
      wfrag[mt][kt] = to_frag(*(const f32x4*)wp, *(const f32x4*)(wp + 4));
      wp += 32;
    }
    const float* up = Uw + h * 28 + q * 8;
    f32x4 u0 = *(const f32x4*)up;
    f32x4 u1 = zero4;
    if (q < 3) u1 = *(const f32x4*)(up + 4);
    ufrag[mt] = to_frag(u0, u1);
    const int hb = mrow + mt * 16 + q * 4;
    bias[mt] = *(const f32x4*)(Wb + hb) + *(const f32x4*)(Ub + hb);
  }

  // S row bases for the two n-tiles (batch rows l15 and 16+l15)
  const int ro0 = l15 * S_STRIDE;
  const int ro1 = (16 + l15) * S_STRIDE;
  const int dcol = mrow + q * 4;                 // D-row base within S row

  // ---- t = 0 (S=0: projection only), write Sbuf[1] ----
  {
    short8 xf0 = to_frag(xa0, xb0);
    short8 xf1 = to_frag(xa1, xb1);
    xa0 = *(const f32x4*)(xp0 + 28); xa1 = *(const f32x4*)(xp1 + 28);
    if (q < 3) { xb0 = *(const f32x4*)(xp0 + 32); xb1 = *(const f32x4*)(xp1 + 32); }
    unsigned short* wp = &Sbuf[1][0];
#pragma unroll
    for (int mt = 0; mt < 2; ++mt) {
      f32x4 d0 = MFMA16(ufrag[mt], xf0, bias[mt], 0, 0, 0);
      f32x4 d1 = MFMA16(ufrag[mt], xf1, bias[mt], 0, 0, 0);
      f32x4 t0 = tanh4(d0);
      f32x4 t1 = tanh4(d1);
      uint2 e0; e0.x = pack2(t0[0], t0[1]); e0.y = pack2(t0[2], t0[3]);
      uint2 e1; e1.x = pack2(t1[0], t1[1]); e1.y = pack2(t1[2], t1[3]);
      *(uint2*)(wp + ro0 + dcol + mt * 16) = e0;
      *(uint2*)(wp + ro1 + dcol + mt * 16) = e1;
    }
  }
  lds_barrier();

  // ---- t = 1 .. 27 ----
  f32x4 acc[2][2];                               // [mt][nt]
#pragma unroll 1
  for (int t = 1; t < T_STEPS; ++t) {
    short8 xf0 = to_frag(xa0, xb0);
    short8 xf1 = to_frag(xa1, xb1);
    if (t < T_STEPS - 1) {                       // issue prefetch for t+1
      const float* n0 = xp0 + (t + 1) * 28;
      const float* n1 = xp1 + (t + 1) * 28;
      xa0 = *(const f32x4*)n0; xa1 = *(const f32x4*)n1;
      if (q < 3) { xb0 = *(const f32x4*)(n0 + 4); xb1 = *(const f32x4*)(n1 + 4); }
    }

    const unsigned short* sb = &Sbuf[t & 1][0] + q * 8;

    // kt = 0 with bias as C-operand
    short8 s0 = load_frag64(sb, ro0);
    short8 s1 = load_frag64(sb, ro1);
#pragma unroll
    for (int mt = 0; mt < 2; ++mt) {
      acc[mt][0] = MFMA16(wfrag[mt][0], s0, bias[mt], 0, 0, 0);
      acc[mt][1] = MFMA16(wfrag[mt][0], s1, bias[mt], 0, 0, 0);
    }
#pragma unroll
    for (int kt = 1; kt < 4; ++kt) {
      s0 = load_frag64(sb, ro0 + kt * 32);
      s1 = load_frag64(sb, ro1 + kt * 32);
#pragma unroll
      for (int mt = 0; mt < 2; ++mt) {
        acc[mt][0] = MFMA16(wfrag[mt][kt], s0, acc[mt][0], 0, 0, 0);
        acc[mt][1] = MFMA16(wfrag[mt][kt], s1, acc[mt][1], 0, 0, 0);
      }
    }
#pragma unroll
    for (int mt = 0; mt < 2; ++mt) {
      acc[mt][0] = MFMA16(ufrag[mt], xf0, acc[mt][0], 0, 0, 0);
      acc[mt][1] = MFMA16(ufrag[mt], xf1, acc[mt][1], 0, 0, 0);
    }

    unsigned short* wp = &Sbuf[(t + 1) & 1][0];
#pragma unroll
    for (int mt = 0; mt < 2; ++mt) {
      f32x4 t0 = tanh4(acc[mt][0]);
      f32x4 t1 = tanh4(acc[mt][1]);
      uint2 e0; e0.x = pack2(t0[0], t0[1]); e0.y = pack2(t0[2], t0[3]);
      uint2 e1; e1.x = pack2(t1[0], t1[1]); e1.y = pack2(t1[2], t1[3]);
      *(uint2*)(wp + ro0 + dcol + mt * 16) = e0;
      *(uint2*)(wp + ro1 + dcol + mt * 16) = e1;
    }
    lds_barrier();
  }

  // ---- epilogue: out[b][c] = sum_h S[b][h]*Vw[c][h] + Vb[c] ----
  // Final S in Sbuf[(27+1)&1] = Sbuf[0].  32 rows x 10 cols; R7 scheme x2.
  {
    const int c0 = tid & 15;        // only c0<10 active
    if (c0 < 10) {
      const float* vp = Vw + c0 * 128;
#pragma unroll
      for (int half = 0; half < 2; ++half) {
        const int r = half * 16 + (tid >> 4);
        const unsigned short* srow = &Sbuf[0][0] + r * S_STRIDE;
        float a0 = Vb[c0];
#pragma unroll
        for (int h = 0; h < 128; h += 4) {
          uint2 d  = *(const uint2*)(srow + h);       // 4 bf16, 8B aligned
          f32x4 v4 = *(const f32x4*)(vp + h);
          a0 += __builtin_bit_cast(float, d.x << 16) * v4[0];
          a0 += __builtin_bit_cast(float, d.x & 0xFFFF0000u) * v4[1];
          a0 += __builtin_bit_cast(float, d.y << 16) * v4[2];
          a0 += __builtin_bit_cast(float, d.y & 0xFFFF0000u) * v4[3];
        }
        out[(size_t)(b0 + r) * 10 + c0] = a0;
      }
    }
  }
}

extern "C" void kernel_launch(void* const* d_in, const int* in_sizes, int n_in,
                              void* d_out, int out_size, void* d_ws, size_t ws_size,
                              hipStream_t stream) {
  const float* x  = (const float*)d_in[0];
  const float* Uw = (const float*)d_in[1];
  const float* Ub = (const float*)d_in[2];
  const float* Ww = (const float*)d_in[3];
  const float* Wb = (const float*)d_in[4];
  const float* Vw = (const float*)d_in[5];
  const float* Vb = (const float*)d_in[6];
  rnn_fused<<<1024, 256, 0, stream>>>(x, Uw, Ub, Ww, Wb, Vw, Vb, (float*)d_out);
}

// Round 8
// 190.409 us; speedup vs baseline: 1.1753x; 1.1753x over previous
//
#include <hip/hip_runtime.h>

// SimpleRNN fused kernel for MI355X (gfx950).  B=32768, T=28, I=28, H=128, C=10.
//
// R15 = R7 (best measured: 91 us dispatch / 200.3 us harness) with two strict
// VALU reductions; all structure byte-identical to R7.
//   Kept verbatim (R7-proven):
//     - whole-x-block prologue staging -> Xbuf[16][900] bf16 (no in-loop
//       global: the 1-step-prefetch variants R11/R14 all lose ~15 us to the
//       per-step vmcnt wait at the top of the loop — HBM latency ~900cy >
//       one step of cover)
//     - Sbuf[2][16*132] double-buffer, 4 waves, wave w owns h [32w,32w+32)
//     - __syncthreads per step (in-loop vmcnt is always 0 -> drain free)
//     - bias-as-MFMA-C, 10 MFMA/wave/step, launch_bounds(256,4), grid 2048
//   Changed:
//     1. tanh via hardware exp2: tanh(x) = 1 - 2/(1+e^{2x}),
//        e^{2x} = v_exp_f32(x*2log2e).  5 insts/elem vs Pade's 9; saturates
//        naturally (exp->inf => 1, exp->0 => -1), no clamp; err ~1e-6
//        (better than Pade's 1.2e-3).  Shortens both issue count and the
//        per-step dependency chain.
//     2. epilogue out^T = Vw*S^T + Vb as one 4-MFMA chain on wave 0
//        (R12-proven mapping; B-frag reads identical to the step's S-reads),
//        replacing the 32-iter scalar dot loop (~320 inst/thread).
// Failed-structure ledger (do not revisit): barrier amortization (R14=0),
// residency knobs (R11/R13, occupancy pins ~36-40%), barrier-free state-in-
// regs (R8/R12, VGPR-bound), launch_bounds >4 (R10 spills).
//
// MFMA 16x16x32 bf16 layouts (m89/m91):
//   A[m=lane&15][k=(lane>>4)*8+j]  B[k=(lane>>4)*8+j][n=lane&15]
//   D[(lane>>4)*4+r][lane&15]

#define T_STEPS 28
#define S_STRIDE 132
#define X_STRIDE 900
#define XSLOTS 3136          // 16 rows * 784 f32 / 4 per dwordx4

typedef __attribute__((ext_vector_type(4))) float f32x4;
typedef __attribute__((ext_vector_type(8))) short short8;

#define MFMA16 __builtin_amdgcn_mfma_f32_16x16x32_bf16

__device__ __forceinline__ unsigned pack2(float lo, float hi) {
#if __has_builtin(__builtin_amdgcn_cvt_pk_bf16_f32)
  auto p = __builtin_amdgcn_cvt_pk_bf16_f32(lo, hi);   // RNE pack, 1 inst
  return __builtin_bit_cast(unsigned, p);
#else
  unsigned a = __builtin_bit_cast(unsigned, lo);
  a += 0x7FFFu + ((a >> 16) & 1u);
  unsigned b = __builtin_bit_cast(unsigned, hi);
  b += 0x7FFFu + ((b >> 16) & 1u);
  return (a >> 16) | (b & 0xFFFF0000u);
#endif
}

__device__ __forceinline__ short8 to_frag(f32x4 a, f32x4 b) {
  union { unsigned u[4]; short8 v; } r;
  r.u[0] = pack2(a[0], a[1]);
  r.u[1] = pack2(a[2], a[3]);
  r.u[2] = pack2(b[0], b[1]);
  r.u[3] = pack2(b[2], b[3]);
  return r.v;
}

__device__ __forceinline__ short8 load_frag64(const unsigned short* sp, int off) {
  // two b64 reads; measured conflict-free at the stride-132-pattern (R1/R3/R5)
  union { uint2 d[2]; short8 v; } r;
  r.d[0] = *(const uint2*)(sp + off);
  r.d[1] = *(const uint2*)(sp + off + 4);
  return r.v;
}

__device__ __forceinline__ float fast_exp2(float a) {
#if __has_builtin(__builtin_amdgcn_exp2f)
  return __builtin_amdgcn_exp2f(a);   // v_exp_f32
#else
  return __exp2f(a);
#endif
}

// tanh(x) = 1 - 2/(1 + e^{2x}); e^{2x} = 2^(x * 2*log2(e)).
// 5 insts/elem (mul, exp, add, rcp, fma).  Saturates naturally:
// x>>0: exp=inf -> rcp=0 -> 1;  x<<0: exp=0 -> rcp(1)=1 -> -1.
__device__ __forceinline__ f32x4 tanh4(f32x4 z) {
  f32x4 t;
#pragma unroll
  for (int i = 0; i < 4; ++i) {
    float e = fast_exp2(z[i] * 2.885390081777927f);
    float r = __builtin_amdgcn_rcpf(1.0f + e);
    t[i] = __builtin_fmaf(r, -2.0f, 1.0f);
  }
  return t;
}

__global__ __launch_bounds__(256, 4) void rnn_fused(
    const float* __restrict__ x,  const float* __restrict__ Uw,
    const float* __restrict__ Ub, const float* __restrict__ Ww,
    const float* __restrict__ Wb, const float* __restrict__ Vw,
    const float* __restrict__ Vb, float* __restrict__ out) {
  __shared__ __align__(16) unsigned short Sbuf[2][16 * S_STRIDE];
  __shared__ __align__(16) unsigned short Xbuf[16 * X_STRIDE];

  const int tid  = threadIdx.x;
  const int w    = tid >> 6;
  const int lane = tid & 63;
  const int l15  = lane & 15;
  const int q    = lane >> 4;           // 0..3
  const int mrow = w * 32;              // h base for this wave (2 m-tiles)
  const int b0   = blockIdx.x * 16;

  const f32x4 zero4 = {0.f, 0.f, 0.f, 0.f};
  const float* xblk = x + (size_t)b0 * 784;

  // ---- prologue A: stage the whole x block -> Xbuf (bf16, k-padded) ----
  // slot s (dwordx4 of f32): global flat offset s*4 (fully coalesced).
  // LDS: row=s/196, g=s%196, t=g/7, j=g%7 -> row*900 + t*32 + j*4.
  {
    f32x4 xr[13];
#pragma unroll
    for (int k = 0; k < 13; ++k) {
      int s = tid + 256 * k;
      if (s < XSLOTS) xr[k] = *(const f32x4*)(xblk + s * 4);
    }
#pragma unroll
    for (int k = 0; k < 13; ++k) {
      int s = tid + 256 * k;
      if (s < XSLOTS) {
        int row = s / 196, g = s - row * 196, tt = g / 7, j = g - tt * 7;
        uint2 d; d.x = pack2(xr[k][0], xr[k][1]); d.y = pack2(xr[k][2], xr[k][3]);
        *(uint2*)(Xbuf + row * X_STRIDE + tt * 32 + j * 4) = d;
        if (j == 0) {   // zero k=28..31 once per (row,t)
          uint2 zz; zz.x = 0u; zz.y = 0u;
          *(uint2*)(Xbuf + row * X_STRIDE + tt * 32 + 28) = zz;
        }
      }
    }
  }

  // ---- prologue B: persistent weight fragments (after staging regs die) ----
  short8 wfrag[2][4];   // [mt][kt]
  short8 ufrag[2];      // [mt], K=32 padded (k>=28 zeroed)
  f32x4  bias[2];       // Ub[h]+Wb[h] at D rows h = mrow + mt*16 + q*4 + r
#pragma unroll
  for (int mt = 0; mt < 2; ++mt) {
    const int h = mrow + mt * 16 + l15;
    const float* wp = Ww + h * 128 + q * 8;
#pragma unroll
    for (int kt = 0; kt < 4; ++kt) {
      wfrag[mt][kt] = to_frag(*(const f32x4*)wp, *(const f32x4*)(wp + 4));
      wp += 32;
    }
    const float* up = Uw + h * 28 + q * 8;
    f32x4 u0 = *(const f32x4*)up;
    f32x4 u1 = zero4;
    if (q < 3) u1 = *(const f32x4*)(up + 4);
    ufrag[mt] = to_frag(u0, u1);
    const int hb = mrow + mt * 16 + q * 4;
    bias[mt] = *(const f32x4*)(Wb + hb) + *(const f32x4*)(Ub + hb);
  }
  __syncthreads();   // Xbuf visible

  const int ro = l15 * S_STRIDE;                 // S row base (batch = l15)
  const int xo = l15 * X_STRIDE + q * 8;         // x frag base
  f32x4 acc[2];

  // ---- t = 0 (S=0: projection only) ----
  {
    short8 xf = load_frag64(&Xbuf[0], xo);
    unsigned short* wp = &Sbuf[1][0];
#pragma unroll
    for (int mt = 0; mt < 2; ++mt) {
      f32x4 d0 = MFMA16(ufrag[mt], xf, bias[mt], 0, 0, 0);
      f32x4 t0 = tanh4(d0);
      uint2 dd; dd.x = pack2(t0[0], t0[1]); dd.y = pack2(t0[2], t0[3]);
      *(uint2*)(wp + ro + mrow + mt * 16 + q * 4) = dd;
    }
  }
  __syncthreads();

  // ---- t = 1 .. 27 : pure LDS/MFMA/VALU, zero global ----
#pragma unroll 1
  for (int t = 1; t < T_STEPS; ++t) {
    short8 xf = load_frag64(&Xbuf[0], xo + t * 32);

    const unsigned short* sp = &Sbuf[t & 1][0] + ro + q * 8;

    // kt = 0 with bias as C-operand
    short8 sA = load_frag64(sp, 0);
#pragma unroll
    for (int mt = 0; mt < 2; ++mt)
      acc[mt] = MFMA16(wfrag[mt][0], sA, bias[mt], 0, 0, 0);
#pragma unroll
    for (int kt = 1; kt < 4; ++kt) {
      sA = load_frag64(sp, kt * 32);
#pragma unroll
      for (int mt = 0; mt < 2; ++mt)
        acc[mt] = MFMA16(wfrag[mt][kt], sA, acc[mt], 0, 0, 0);
    }
#pragma unroll
    for (int mt = 0; mt < 2; ++mt)
      acc[mt] = MFMA16(ufrag[mt], xf, acc[mt], 0, 0, 0);

    unsigned short* wp = &Sbuf[(t + 1) & 1][0];
#pragma unroll
    for (int mt = 0; mt < 2; ++mt) {
      f32x4 th = tanh4(acc[mt]);
      uint2 dd; dd.x = pack2(th[0], th[1]); dd.y = pack2(th[2], th[3]);
      *(uint2*)(wp + ro + mrow + mt * 16 + q * 4) = dd;
    }
    __syncthreads();
  }

  // ---- epilogue: out^T[c][b] = Vw*S^T + Vb as one 4-MFMA chain (wave 0) ----
  // Final S in Sbuf[0].  A = Vw rows c=l15 (<10, else 0); B = S^T read with
  // the step's exact S-frag pattern; D rows c = q*4+r, col b = l15.
  if (w == 0) {
    short8 vfrag[4];
    const float* vp = Vw + l15 * 128 + q * 8;
#pragma unroll
    for (int kt = 0; kt < 4; ++kt) {
      f32x4 v0 = zero4, v1 = zero4;
      if (l15 < 10) {
        v0 = *(const f32x4*)(vp + kt * 32);
        v1 = *(const f32x4*)(vp + kt * 32 + 4);
      }
      vfrag[kt] = to_frag(v0, v1);
    }
    const unsigned short* sp = &Sbuf[0][0] + ro + q * 8;
    f32x4 o;
#pragma unroll
    for (int r = 0; r < 4; ++r) {
      const int c = q * 4 + r;
      o[r] = (c < 10) ? Vb[c] : 0.f;
    }
#pragma unroll
    for (int kt = 0; kt < 4; ++kt)
      o = MFMA16(vfrag[kt], load_frag64(sp, kt * 32), o, 0, 0, 0);
#pragma unroll
    for (int r = 0; r < 4; ++r) {
      const int c = q * 4 + r;
      if (c < 10) out[(size_t)(b0 + l15) * 10 + c] = o[r];
    }
  }
}

extern "C" void kernel_launch(void* const* d_in, const int* in_sizes, int n_in,
                              void* d_out, int out_size, void* d_ws, size_t ws_size,
                              hipStream_t stream) {
  const float* x  = (const float*)d_in[0];
  const float* Uw = (const float*)d_in[1];
  const float* Ub = (const float*)d_in[2];
  const float* Ww = (const float*)d_in[3];
  const float* Wb = (const float*)d_in[4];
  const float* Vw = (const float*)d_in[5];
  const float* Vb = (const float*)d_in[6];
  rnn_fused<<<2048, 256, 0, stream>>>(x, Uw, Ub, Ww, Wb, Vw, Vb, (float*)d_out);
}